// Round 3
// baseline (3161.766 us; speedup 1.0000x reference)
//
#include <hip/hip_runtime.h>

#define NN 100000
#define NE 1600000
#define D 128
#define LEAKY 0.01f
#define BNEPS 1e-5f

#define G 256        // sort groups (workgroups)
#define CHUNK 6250   // NE / G exactly
#define B 782        // ceil(NN/128) dst-buckets
#define BSHIFT 7
#define BMASK 127

// ---------------- degree + norm ----------------

__global__ void deg_kernel(const int* __restrict__ src, const int* __restrict__ dst,
                           int* __restrict__ deg) {
    int e = blockIdx.x * blockDim.x + threadIdx.x;
    if (e < NE) {
        atomicAdd(&deg[src[e]], 1);        // out-degree
        atomicAdd(&deg[NN + dst[e]], 1);   // in-degree
    }
}

__global__ void norm_kernel(const int* __restrict__ deg, float* __restrict__ norm) {
    int i = blockIdx.x * blockDim.x + threadIdx.x;
    if (i < NN) {
        norm[i]      = rsqrtf((float)(deg[i] + 1));      // +1 = self-loop
        norm[NN + i] = rsqrtf((float)(deg[NN + i] + 1));
    }
}

// ---------------- counting sort by dst bucket ----------------
// hist[b*G + g] = #edges in group g hitting bucket b (bucket-major for scan)

__global__ __launch_bounds__(256) void hist_kernel(const int* __restrict__ dst,
                                                   int* __restrict__ hist) {
    __shared__ int h[B];
    for (int i = threadIdx.x; i < B; i += 256) h[i] = 0;
    __syncthreads();
    int g = blockIdx.x;
    const int* dp = dst + g * CHUNK;
    for (int k = threadIdx.x; k < CHUNK; k += 256)
        atomicAdd(&h[dp[k] >> BSHIFT], 1);
    __syncthreads();
    for (int i = threadIdx.x; i < B; i += 256) hist[i * G + g] = h[i];
}

// exclusive scan of hist (length B*G = 782*256, exactly 782 blocks of 256)

__global__ void scanA(const int* __restrict__ a, int* __restrict__ bsum) {
    __shared__ int sm[256];
    int t = threadIdx.x;
    sm[t] = a[blockIdx.x * 256 + t];
    __syncthreads();
    for (int s = 128; s > 0; s >>= 1) {
        if (t < s) sm[t] += sm[t + s];
        __syncthreads();
    }
    if (t == 0) bsum[blockIdx.x] = sm[0];
}

__global__ void scanB(const int* __restrict__ bsum, int* __restrict__ boffs) {
    // one wave, shuffle-scan 782 block sums
    int lane = threadIdx.x;
    int run = 0;
    for (int base = 0; base < B; base += 64) {
        int i = base + lane;
        int v = (i < B) ? bsum[i] : 0;
        int orig = v;
        for (int off = 1; off < 64; off <<= 1) {
            int t = __shfl_up(v, off);
            if (lane >= off) v += t;
        }
        if (i < B) boffs[i] = run + v - orig;   // exclusive
        run += __shfl(v, 63);
    }
}

__global__ void scanC(const int* __restrict__ a, const int* __restrict__ boffs,
                      int* __restrict__ offs) {
    __shared__ int sm[256];
    int t = threadIdx.x;
    int i = blockIdx.x * 256 + t;
    int v = a[i];
    sm[t] = v;
    __syncthreads();
    for (int off = 1; off < 256; off <<= 1) {
        int x = (t >= off) ? sm[t - off] : 0;
        __syncthreads();
        sm[t] += x;
        __syncthreads();
    }
    offs[i] = boffs[blockIdx.x] + sm[t] - v;    // exclusive
}

__global__ __launch_bounds__(256) void sort_kernel(const int* __restrict__ src,
                                                   const int* __restrict__ dst,
                                                   const int* __restrict__ offs,
                                                   unsigned* __restrict__ ebuf) {
    __shared__ int cur[B];
    int g = blockIdx.x;
    for (int i = threadIdx.x; i < B; i += 256) cur[i] = offs[i * G + g];
    __syncthreads();
    const int* sp = src + g * CHUNK;
    const int* dp = dst + g * CHUNK;
    for (int k = threadIdx.x; k < CHUNK; k += 256) {
        int d = dp[k], s = sp[k];
        int pos = atomicAdd(&cur[d >> BSHIFT], 1);
        ebuf[pos] = ((unsigned)(d & BMASK) << 17) | (unsigned)s;   // src < 2^17
    }
}

// ---------------- bucket aggregation ----------------
// One block per 128-node bucket. acc[128][128] f32 in LDS (64 KB). Lane i owns
// columns i and i+64 -> ds ops are 2-way bank aliased (free). Self-loop folded
// into init; each output row written exactly once. 4 waves, 4 edges in flight
// per wave.

template<bool L0>
__global__ __launch_bounds__(256) void bucket_agg(
    const unsigned* __restrict__ ebuf, const int* __restrict__ offs,
    const float* __restrict__ h, const float* __restrict__ norm_s,
    float* __restrict__ agg)
{
    __shared__ float acc[D * D];
    const int b = blockIdx.x;
    const int wave = threadIdx.x >> 6;
    const int lane = threadIdx.x & 63;
    const int c0 = lane, c1 = lane + 64;

    // init with self-loop contribution
    for (int r = wave * 32; r < wave * 32 + 32; ++r) {
        int node = b * 128 + r;
        float v0 = 0.f, v1 = 0.f;
        if (node < NN) {
            v0 = h[(size_t)node * D + c0];
            v1 = h[(size_t)node * D + c1];
            if (L0) { float w = norm_s[node]; v0 *= w; v1 *= w; }
        }
        acc[r * D + c0] = v0;
        acc[r * D + c1] = v1;
    }
    __syncthreads();

    const int s = offs[b * G];
    const int e = (b == B - 1) ? NE : offs[(b + 1) * G];
    for (int base = s + wave * 4; base < e; base += 16) {
        #pragma unroll
        for (int j = 0; j < 4; ++j) {
            bool ok = (base + j < e);
            unsigned u = ebuf[base + (ok ? j : 0)];
            int sr = u & 0x1FFFF;
            int dl = u >> 17;
            float v0 = h[(size_t)sr * D + c0];
            float v1 = h[(size_t)sr * D + c1];
            float wt = ok ? (L0 ? norm_s[sr] : 1.0f) : 0.0f;
            atomicAdd(&acc[dl * D + c0], v0 * wt);
            atomicAdd(&acc[dl * D + c1], v1 * wt);
        }
    }
    __syncthreads();

    for (int r = wave * 32; r < wave * 32 + 32; ++r) {
        int node = b * 128 + r;
        if (node < NN) {
            agg[(size_t)node * D + c0] = acc[r * D + c0];
            agg[(size_t)node * D + c1] = acc[r * D + c1];
        }
    }
}

// ---------------- fused GEMM (+ norm_dst, bias, BN, leaky, norm_src) ----------------

template<bool LAYER0>
__global__ __launch_bounds__(256, 2) void gemm_kernel(
    const float* __restrict__ agg, const float* __restrict__ W,
    const float* __restrict__ bias,
    const float* __restrict__ norm_s, const float* __restrict__ norm_d,
    const float* __restrict__ gamma, const float* __restrict__ beta,
    const float* __restrict__ rmean, const float* __restrict__ rvar,
    float* __restrict__ out0)
{
    __shared__ float Wl[D * D];
    for (int idx = threadIdx.x; idx < D * D / 4; idx += 256)
        ((float4*)Wl)[idx] = ((const float4*)W)[idx];
    __syncthreads();

    const int wave = threadIdx.x >> 6;
    const int lane = threadIdx.x & 63;
    const int j0 = lane, j1 = lane + 64;

    const float b0 = bias[j0], b1v = bias[j1];
    float s0 = 0.f, sh0 = 0.f, s1 = 0.f, sh1 = 0.f;
    if (LAYER0) {
        s0  = gamma[j0] * rsqrtf(rvar[j0] + BNEPS);
        sh0 = beta[j0] - rmean[j0] * s0;
        s1  = gamma[j1] * rsqrtf(rvar[j1] + BNEPS);
        sh1 = beta[j1] - rmean[j1] * s1;
    }

    const int ROWS = 4;
    const int wave_id = blockIdx.x * 4 + wave;
    const int nwaves = gridDim.x * 4;
    for (int base = wave_id * ROWS; base < NN; base += nwaves * ROWS) {
        float acc[ROWS][2] = {};
        const float* rp = agg + (size_t)base * D;
        #pragma unroll 4
        for (int k = 0; k < D; k += 4) {
            float vv[ROWS][4];
            *(float4*)&vv[0][0] = *(const float4*)(rp + 0 * D + k);
            *(float4*)&vv[1][0] = *(const float4*)(rp + 1 * D + k);
            *(float4*)&vv[2][0] = *(const float4*)(rp + 2 * D + k);
            *(float4*)&vv[3][0] = *(const float4*)(rp + 3 * D + k);
            #pragma unroll
            for (int kk = 0; kk < 4; ++kk) {
                float w0 = Wl[(k + kk) * D + j0];
                float w1 = Wl[(k + kk) * D + j1];
                #pragma unroll
                for (int r = 0; r < ROWS; ++r) {
                    acc[r][0] = fmaf(vv[r][kk], w0, acc[r][0]);
                    acc[r][1] = fmaf(vv[r][kk], w1, acc[r][1]);
                }
            }
        }
        #pragma unroll
        for (int r = 0; r < ROWS; ++r) {
            int row = base + r;
            float nd = norm_d[row];
            float o0 = acc[r][0] * nd + b0;
            float o1 = acc[r][1] * nd + b1v;
            if (LAYER0) {
                o0 = o0 * s0 + sh0;
                o1 = o1 * s1 + sh1;
                o0 = o0 > 0.f ? o0 : LEAKY * o0;
                o1 = o1 > 0.f ? o1 : LEAKY * o1;
                float ns = norm_s[row];
                o0 *= ns; o1 *= ns;
            }
            out0[(size_t)row * D + j0] = o0;
            out0[(size_t)row * D + j1] = o1;
        }
    }
}

// ---------------- launch ----------------

extern "C" void kernel_launch(void* const* d_in, const int* in_sizes, int n_in,
                              void* d_out, int out_size, void* d_ws, size_t ws_size,
                              hipStream_t stream) {
    const float* x     = (const float*)d_in[0];
    const int*   src   = (const int*)d_in[1];
    const int*   dst   = (const int*)d_in[2];
    const float* W1    = (const float*)d_in[3];
    const float* b1    = (const float*)d_in[4];
    const float* W2    = (const float*)d_in[5];
    const float* b2    = (const float*)d_in[6];
    const float* gamma = (const float*)d_in[7];
    const float* beta  = (const float*)d_in[8];
    const float* rmean = (const float*)d_in[9];
    const float* rvar  = (const float*)d_in[10];
    float* out = (float*)d_out;

    // ws layout (4B units)
    float*    buf1  = (float*)d_ws;                         // NN*D aggregator
    float*    norm  = buf1 + (size_t)NN * D;                // 2N f32
    int*      hist  = (int*)(norm + 2 * NN);                // B*G int  (deg overlays here)
    int*      offs  = hist + B * G;                         // B*G int
    int*      bsum  = offs + B * G;                         // B int
    int*      boffs = bsum + B;                             // B int
    unsigned* ebuf  = (unsigned*)(boffs + B);               // NE u32
    float* norm_s = norm;
    float* norm_d = norm + NN;
    int*   deg    = hist;   // deg (2N int) dead after norm_kernel; hist reuses it

    hipMemsetAsync(deg, 0, 2 * NN * sizeof(int), stream);
    deg_kernel<<<(NE + 255) / 256, 256, 0, stream>>>(src, dst, deg);
    norm_kernel<<<(NN + 255) / 256, 256, 0, stream>>>(deg, norm);

    // counting sort by dst bucket
    hist_kernel<<<G, 256, 0, stream>>>(dst, hist);
    scanA<<<B * G / 256, 256, 0, stream>>>(hist, bsum);
    scanB<<<1, 64, 0, stream>>>(bsum, boffs);
    scanC<<<B * G / 256, 256, 0, stream>>>(hist, boffs, offs);
    sort_kernel<<<G, 256, 0, stream>>>(src, dst, offs, ebuf);

    // layer 0
    bucket_agg<true><<<B, 256, 0, stream>>>(ebuf, offs, x, norm_s, buf1);
    gemm_kernel<true><<<512, 256, 0, stream>>>(buf1, W1, b1, norm_s, norm_d,
                                               gamma, beta, rmean, rvar, out);
    // layer 1 (gather source = d_out; norm_src already folded into it)
    bucket_agg<false><<<B, 256, 0, stream>>>(ebuf, offs, out, nullptr, buf1);
    gemm_kernel<false><<<512, 256, 0, stream>>>(buf1, W2, b2, norm_s, norm_d,
                                                nullptr, nullptr, nullptr, nullptr, out);
}

// Round 4
// 675.323 us; speedup vs baseline: 4.6819x; 4.6819x over previous
//
#include <hip/hip_runtime.h>

#define NN 100000
#define NE 1600000
#define D 128
#define LEAKY 0.01f
#define BNEPS 1e-5f

#define G 256        // sort groups (workgroups)
#define CHUNK 6250   // NE / G exactly
#define B 782        // ceil(NN/128) dst-buckets
#define BSHIFT 7
#define BMASK 127

// ---------------- out-degree + norm_s (in-degree comes from local_sort) ----------

__global__ void deg_src_kernel(const int* __restrict__ src, int* __restrict__ deg) {
    int e = blockIdx.x * blockDim.x + threadIdx.x;
    if (e < NE) atomicAdd(&deg[src[e]], 1);
}

__global__ void norm_s_kernel(const int* __restrict__ deg, float* __restrict__ norm_s) {
    int i = blockIdx.x * blockDim.x + threadIdx.x;
    if (i < NN) norm_s[i] = rsqrtf((float)(deg[i] + 1));   // +1 = self-loop
}

// ---------------- counting sort by dst bucket ----------------
// hist[b*G + g] = #edges in group g hitting bucket b (bucket-major for scan)

__global__ __launch_bounds__(256) void hist_kernel(const int* __restrict__ dst,
                                                   int* __restrict__ hist) {
    __shared__ int h[B];
    for (int i = threadIdx.x; i < B; i += 256) h[i] = 0;
    __syncthreads();
    int g = blockIdx.x;
    const int* dp = dst + g * CHUNK;
    for (int k = threadIdx.x; k < CHUNK; k += 256)
        atomicAdd(&h[dp[k] >> BSHIFT], 1);
    __syncthreads();
    for (int i = threadIdx.x; i < B; i += 256) hist[i * G + g] = h[i];
}

__global__ void scanA(const int* __restrict__ a, int* __restrict__ bsum) {
    __shared__ int sm[256];
    int t = threadIdx.x;
    sm[t] = a[blockIdx.x * 256 + t];
    __syncthreads();
    for (int s = 128; s > 0; s >>= 1) {
        if (t < s) sm[t] += sm[t + s];
        __syncthreads();
    }
    if (t == 0) bsum[blockIdx.x] = sm[0];
}

__global__ void scanB(const int* __restrict__ bsum, int* __restrict__ boffs) {
    // one wave, shuffle-scan 782 block sums
    int lane = threadIdx.x;
    int run = 0;
    for (int base = 0; base < B; base += 64) {
        int i = base + lane;
        int v = (i < B) ? bsum[i] : 0;
        int orig = v;
        for (int off = 1; off < 64; off <<= 1) {
            int t = __shfl_up(v, off);
            if (lane >= off) v += t;
        }
        if (i < B) boffs[i] = run + v - orig;   // exclusive
        run += __shfl(v, 63);
    }
}

__global__ void scanC(const int* __restrict__ a, const int* __restrict__ boffs,
                      int* __restrict__ offs) {
    __shared__ int sm[256];
    int t = threadIdx.x;
    int i = blockIdx.x * 256 + t;
    int v = a[i];
    sm[t] = v;
    __syncthreads();
    for (int off = 1; off < 256; off <<= 1) {
        int x = (t >= off) ? sm[t - off] : 0;
        __syncthreads();
        sm[t] += x;
        __syncthreads();
    }
    offs[i] = boffs[blockIdx.x] + sm[t] - v;    // exclusive
}

__global__ __launch_bounds__(256) void sort_kernel(const int* __restrict__ src,
                                                   const int* __restrict__ dst,
                                                   const int* __restrict__ offs,
                                                   unsigned* __restrict__ ebuf) {
    __shared__ int cur[B];
    int g = blockIdx.x;
    for (int i = threadIdx.x; i < B; i += 256) cur[i] = offs[i * G + g];
    __syncthreads();
    const int* sp = src + g * CHUNK;
    const int* dp = dst + g * CHUNK;
    for (int k = threadIdx.x; k < CHUNK; k += 256) {
        int d = dp[k], s = sp[k];
        int pos = atomicAdd(&cur[d >> BSHIFT], 1);
        ebuf[pos] = ((unsigned)(d & BMASK) << 17) | (unsigned)s;   // src < 2^17
    }
}

// ---------------- per-bucket local sort: bucket order -> per-node CSR ----------
// One block per bucket. Reads its exclusive ebuf range into registers,
// histograms dst (=> in-degree => norm_d), scans 128 counters, rewrites the
// SAME range in per-node order (src only). Writes are contiguous; reads all
// complete before any write (register-staged + barrier).

__global__ __launch_bounds__(256) void local_sort(
    const int* __restrict__ offs, unsigned* __restrict__ ebuf,
    int* __restrict__ row, float* __restrict__ norm_d)
{
    __shared__ int cnt[128];
    __shared__ int sc[128];
    const int b = blockIdx.x;
    const int t = threadIdx.x;
    const int s = offs[b * G];
    const int e = (b == B - 1) ? NE : offs[(b + 1) * G];
    if (t < 128) cnt[t] = 0;
    __syncthreads();

    unsigned ent[16];   // 16*256 = 4096 capacity; bucket mean 2048, sd ~45
    int nent = 0;
    for (int k = s + t; k < e && nent < 16; k += 256) {
        unsigned u = ebuf[k];
        ent[nent++] = u;
        atomicAdd(&cnt[u >> 17], 1);
    }
    __syncthreads();

    if (t < 128) sc[t] = cnt[t];
    __syncthreads();
    for (int off = 1; off < 128; off <<= 1) {
        int v = 0;
        if (t < 128 && t >= off) v = sc[t - off];
        __syncthreads();
        if (t < 128) sc[t] += v;
        __syncthreads();
    }
    if (t < 128) {
        int st = s + sc[t] - cnt[t];   // exclusive start
        int node = b * 128 + t;
        if (node < NN) {
            row[node] = st;
            norm_d[node] = rsqrtf((float)(cnt[t] + 1));
        }
        cnt[t] = st;                   // becomes cursor
    }
    if (b == B - 1 && t == 0) row[NN] = NE;
    __syncthreads();

    for (int i = 0; i < nent; ++i) {
        unsigned u = ent[i];
        int pos = atomicAdd(&cnt[u >> 17], 1);
        ebuf[pos] = u & 0x1FFFFu;      // strip bucket bits -> plain src id
    }
}

// ---------------- CSR gather-aggregate (round-2 structure) ----------------

template<bool L0>
__global__ __launch_bounds__(256) void csr_agg(
    const int* __restrict__ row, const int* __restrict__ csr,
    const float* __restrict__ h, const float* __restrict__ norm_s,
    float* __restrict__ agg)
{
    int i = blockIdx.x * 4 + (threadIdx.x >> 6);
    if (i >= NN) return;
    int lane = threadIdx.x & 63;
    int c = lane * 2;

    float2 acc;
    {
        float2 v = *(const float2*)(h + (size_t)i * D + c);
        float w = L0 ? norm_s[i] : 1.0f;
        acc.x = v.x * w; acc.y = v.y * w;
    }

    int start = row[i], end = row[i + 1];
    for (int base = start; base < end; base += 64) {
        int n = end - base; if (n > 64) n = 64;
        int sv = csr[base + (lane < n ? lane : 0)];
        float nsv = L0 ? norm_s[sv] : 1.0f;
        int j = 0;
        for (; j + 4 <= n; j += 4) {
            int s0 = __shfl(sv, j), s1 = __shfl(sv, j + 1);
            int s2 = __shfl(sv, j + 2), s3 = __shfl(sv, j + 3);
            float2 v0 = *(const float2*)(h + (size_t)s0 * D + c);
            float2 v1 = *(const float2*)(h + (size_t)s1 * D + c);
            float2 v2 = *(const float2*)(h + (size_t)s2 * D + c);
            float2 v3 = *(const float2*)(h + (size_t)s3 * D + c);
            if (L0) {
                float w0 = __shfl(nsv, j), w1 = __shfl(nsv, j + 1);
                float w2 = __shfl(nsv, j + 2), w3 = __shfl(nsv, j + 3);
                acc.x = fmaf(v0.x, w0, acc.x); acc.y = fmaf(v0.y, w0, acc.y);
                acc.x = fmaf(v1.x, w1, acc.x); acc.y = fmaf(v1.y, w1, acc.y);
                acc.x = fmaf(v2.x, w2, acc.x); acc.y = fmaf(v2.y, w2, acc.y);
                acc.x = fmaf(v3.x, w3, acc.x); acc.y = fmaf(v3.y, w3, acc.y);
            } else {
                acc.x += v0.x + v1.x + v2.x + v3.x;
                acc.y += v0.y + v1.y + v2.y + v3.y;
            }
        }
        for (; j < n; ++j) {
            int s = __shfl(sv, j);
            float2 v = *(const float2*)(h + (size_t)s * D + c);
            float w = L0 ? __shfl(nsv, j) : 1.0f;
            acc.x = fmaf(v.x, w, acc.x);
            acc.y = fmaf(v.y, w, acc.y);
        }
    }
    *(float2*)(agg + (size_t)i * D + c) = acc;
}

// ---------------- fused GEMM (+ norm_dst, bias, BN, leaky, norm_src) ----------------

template<bool LAYER0>
__global__ __launch_bounds__(256, 2) void gemm_kernel(
    const float* __restrict__ agg, const float* __restrict__ W,
    const float* __restrict__ bias,
    const float* __restrict__ norm_s, const float* __restrict__ norm_d,
    const float* __restrict__ gamma, const float* __restrict__ beta,
    const float* __restrict__ rmean, const float* __restrict__ rvar,
    float* __restrict__ out0)
{
    __shared__ float Wl[D * D];
    for (int idx = threadIdx.x; idx < D * D / 4; idx += 256)
        ((float4*)Wl)[idx] = ((const float4*)W)[idx];
    __syncthreads();

    const int wave = threadIdx.x >> 6;
    const int lane = threadIdx.x & 63;
    const int j0 = lane, j1 = lane + 64;

    const float b0 = bias[j0], b1v = bias[j1];
    float s0 = 0.f, sh0 = 0.f, s1 = 0.f, sh1 = 0.f;
    if (LAYER0) {
        s0  = gamma[j0] * rsqrtf(rvar[j0] + BNEPS);
        sh0 = beta[j0] - rmean[j0] * s0;
        s1  = gamma[j1] * rsqrtf(rvar[j1] + BNEPS);
        sh1 = beta[j1] - rmean[j1] * s1;
    }

    const int ROWS = 4;
    const int wave_id = blockIdx.x * 4 + wave;
    const int nwaves = gridDim.x * 4;
    for (int base = wave_id * ROWS; base < NN; base += nwaves * ROWS) {
        float acc[ROWS][2] = {};
        const float* rp = agg + (size_t)base * D;
        #pragma unroll 4
        for (int k = 0; k < D; k += 4) {
            float vv[ROWS][4];
            *(float4*)&vv[0][0] = *(const float4*)(rp + 0 * D + k);
            *(float4*)&vv[1][0] = *(const float4*)(rp + 1 * D + k);
            *(float4*)&vv[2][0] = *(const float4*)(rp + 2 * D + k);
            *(float4*)&vv[3][0] = *(const float4*)(rp + 3 * D + k);
            #pragma unroll
            for (int kk = 0; kk < 4; ++kk) {
                float w0 = Wl[(k + kk) * D + j0];
                float w1 = Wl[(k + kk) * D + j1];
                #pragma unroll
                for (int r = 0; r < ROWS; ++r) {
                    acc[r][0] = fmaf(vv[r][kk], w0, acc[r][0]);
                    acc[r][1] = fmaf(vv[r][kk], w1, acc[r][1]);
                }
            }
        }
        #pragma unroll
        for (int r = 0; r < ROWS; ++r) {
            int row = base + r;
            float nd = norm_d[row];
            float o0 = acc[r][0] * nd + b0;
            float o1 = acc[r][1] * nd + b1v;
            if (LAYER0) {
                o0 = o0 * s0 + sh0;
                o1 = o1 * s1 + sh1;
                o0 = o0 > 0.f ? o0 : LEAKY * o0;
                o1 = o1 > 0.f ? o1 : LEAKY * o1;
                float ns = norm_s[row];
                o0 *= ns; o1 *= ns;
            }
            out0[(size_t)row * D + j0] = o0;
            out0[(size_t)row * D + j1] = o1;
        }
    }
}

// ---------------- launch ----------------

extern "C" void kernel_launch(void* const* d_in, const int* in_sizes, int n_in,
                              void* d_out, int out_size, void* d_ws, size_t ws_size,
                              hipStream_t stream) {
    const float* x     = (const float*)d_in[0];
    const int*   src   = (const int*)d_in[1];
    const int*   dst   = (const int*)d_in[2];
    const float* W1    = (const float*)d_in[3];
    const float* b1    = (const float*)d_in[4];
    const float* W2    = (const float*)d_in[5];
    const float* b2    = (const float*)d_in[6];
    const float* gamma = (const float*)d_in[7];
    const float* beta  = (const float*)d_in[8];
    const float* rmean = (const float*)d_in[9];
    const float* rvar  = (const float*)d_in[10];
    float* out = (float*)d_out;

    // ws layout (4B units)
    float*    buf1  = (float*)d_ws;                     // NN*D aggregator
    float*    norm  = buf1 + (size_t)NN * D;            // 2N f32
    int*      hist  = (int*)(norm + 2 * NN);            // B*G int; row[] aliases after scanC
    int*      offs  = hist + B * G;                     // B*G int
    int*      bsum  = offs + B * G;                     // B int
    int*      boffs = bsum + B;                         // B int
    unsigned* ebuf  = (unsigned*)(boffs + B);           // NE u32
    float* norm_s = norm;
    float* norm_d = norm + NN;
    int*   row    = hist;                // aliases hist (dead after scanC)
    int*   deg_s  = (int*)ebuf;          // aliases ebuf head (dead before sort_kernel)

    // out-degree (src) -> norm_s ; deg_s lives in ebuf region, extracted before sort
    hipMemsetAsync(deg_s, 0, NN * sizeof(int), stream);
    deg_src_kernel<<<(NE + 255) / 256, 256, 0, stream>>>(src, deg_s);
    norm_s_kernel<<<(NN + 255) / 256, 256, 0, stream>>>(deg_s, norm_s);

    // counting sort by dst bucket, then per-bucket local sort -> per-node CSR
    hist_kernel<<<G, 256, 0, stream>>>(dst, hist);
    scanA<<<B * G / 256, 256, 0, stream>>>(hist, bsum);
    scanB<<<1, 64, 0, stream>>>(bsum, boffs);
    scanC<<<B * G / 256, 256, 0, stream>>>(hist, boffs, offs);
    sort_kernel<<<G, 256, 0, stream>>>(src, dst, offs, ebuf);
    local_sort<<<B, 256, 0, stream>>>(offs, ebuf, row, norm_d);

    const int AGG_BLOCKS = (NN + 3) / 4;
    // layer 0: agg = selfloop + sum_e x[src]*ns[src]
    csr_agg<true><<<AGG_BLOCKS, 256, 0, stream>>>(row, (const int*)ebuf, x, norm_s, buf1);
    gemm_kernel<true><<<512, 256, 0, stream>>>(buf1, W1, b1, norm_s, norm_d,
                                               gamma, beta, rmean, rvar, out);
    // layer 1 (gather source = d_out; norm_src already folded into it)
    csr_agg<false><<<AGG_BLOCKS, 256, 0, stream>>>(row, (const int*)ebuf, out, nullptr, buf1);
    gemm_kernel<false><<<512, 256, 0, stream>>>(buf1, W2, b2, norm_s, norm_d,
                                                nullptr, nullptr, nullptr, nullptr, out);
}

// Round 5
// 580.951 us; speedup vs baseline: 5.4424x; 1.1624x over previous
//
#include <hip/hip_runtime.h>

#define NN 100000
#define NE 1600000
#define D 128
#define LEAKY 0.01f
#define BNEPS 1e-5f

#define G 256        // sort groups (workgroups)
#define CHUNK 6250   // NE / G exactly
#define B 782        // ceil(NN/128) dst-buckets
#define BSHIFT 7
#define BMASK 127

// round-to-nearest-even f32 -> bf16 (returns low 16 bits)
__device__ __forceinline__ unsigned f2bf(float f) {
    unsigned u = __float_as_uint(f);
    return (u + 0x7fffu + ((u >> 16) & 1u)) >> 16;
}

// ---------------- out-degree + norm_s (in-degree comes from local_sort) ----------

__global__ void deg_src_kernel(const int* __restrict__ src, int* __restrict__ deg) {
    int e = blockIdx.x * blockDim.x + threadIdx.x;
    if (e < NE) atomicAdd(&deg[src[e]], 1);
}

__global__ void norm_s_kernel(const int* __restrict__ deg, float* __restrict__ norm_s) {
    int i = blockIdx.x * blockDim.x + threadIdx.x;
    if (i < NN) norm_s[i] = rsqrtf((float)(deg[i] + 1));   // +1 = self-loop
}

// ---------------- x * norm_s -> bf16 gather source ----------------

__global__ __launch_bounds__(256) void conv_kernel(const float* __restrict__ x,
                                                   const float* __restrict__ norm_s,
                                                   unsigned* __restrict__ hb) {
    int t = blockIdx.x * 256 + threadIdx.x;     // one u32 pair per thread
    if (t >= NN * 64) return;
    float ns = norm_s[t >> 6];
    float2 v = ((const float2*)x)[t];
    hb[t] = f2bf(v.x * ns) | (f2bf(v.y * ns) << 16);
}

// ---------------- counting sort by dst bucket ----------------
// hist[b*G + g] = #edges in group g hitting bucket b (bucket-major for scan)

__global__ __launch_bounds__(256) void hist_kernel(const int* __restrict__ dst,
                                                   int* __restrict__ hist) {
    __shared__ int h[B];
    for (int i = threadIdx.x; i < B; i += 256) h[i] = 0;
    __syncthreads();
    int g = blockIdx.x;
    const int* dp = dst + g * CHUNK;
    for (int k = threadIdx.x; k < CHUNK; k += 256)
        atomicAdd(&h[dp[k] >> BSHIFT], 1);
    __syncthreads();
    for (int i = threadIdx.x; i < B; i += 256) hist[i * G + g] = h[i];
}

__global__ void scanA(const int* __restrict__ a, int* __restrict__ bsum) {
    __shared__ int sm[256];
    int t = threadIdx.x;
    sm[t] = a[blockIdx.x * 256 + t];
    __syncthreads();
    for (int s = 128; s > 0; s >>= 1) {
        if (t < s) sm[t] += sm[t + s];
        __syncthreads();
    }
    if (t == 0) bsum[blockIdx.x] = sm[0];
}

__global__ void scanB(const int* __restrict__ bsum, int* __restrict__ boffs) {
    int lane = threadIdx.x;
    int run = 0;
    for (int base = 0; base < B; base += 64) {
        int i = base + lane;
        int v = (i < B) ? bsum[i] : 0;
        int orig = v;
        for (int off = 1; off < 64; off <<= 1) {
            int t = __shfl_up(v, off);
            if (lane >= off) v += t;
        }
        if (i < B) boffs[i] = run + v - orig;   // exclusive
        run += __shfl(v, 63);
    }
}

__global__ void scanC(const int* __restrict__ a, const int* __restrict__ boffs,
                      int* __restrict__ offs) {
    __shared__ int sm[256];
    int t = threadIdx.x;
    int i = blockIdx.x * 256 + t;
    int v = a[i];
    sm[t] = v;
    __syncthreads();
    for (int off = 1; off < 256; off <<= 1) {
        int x = (t >= off) ? sm[t - off] : 0;
        __syncthreads();
        sm[t] += x;
        __syncthreads();
    }
    offs[i] = boffs[blockIdx.x] + sm[t] - v;    // exclusive
}

__global__ __launch_bounds__(256) void sort_kernel(const int* __restrict__ src,
                                                   const int* __restrict__ dst,
                                                   const int* __restrict__ offs,
                                                   unsigned* __restrict__ ebuf) {
    __shared__ int cur[B];
    int g = blockIdx.x;
    for (int i = threadIdx.x; i < B; i += 256) cur[i] = offs[i * G + g];
    __syncthreads();
    const int* sp = src + g * CHUNK;
    const int* dp = dst + g * CHUNK;
    for (int k = threadIdx.x; k < CHUNK; k += 256) {
        int d = dp[k], s = sp[k];
        int pos = atomicAdd(&cur[d >> BSHIFT], 1);
        ebuf[pos] = ((unsigned)(d & BMASK) << 17) | (unsigned)s;   // src < 2^17
    }
}

// ---------------- per-bucket local sort: bucket order -> per-node CSR ----------

__global__ __launch_bounds__(256) void local_sort(
    const int* __restrict__ offs, unsigned* __restrict__ ebuf,
    int* __restrict__ row, float* __restrict__ norm_d)
{
    __shared__ int cnt[128];
    __shared__ int sc[128];
    const int b = blockIdx.x;
    const int t = threadIdx.x;
    const int s = offs[b * G];
    const int e = (b == B - 1) ? NE : offs[(b + 1) * G];
    if (t < 128) cnt[t] = 0;
    __syncthreads();

    unsigned ent[16];   // 16*256 = 4096 capacity; bucket mean 2048, sd ~45
    int nent = 0;
    for (int k = s + t; k < e && nent < 16; k += 256) {
        unsigned u = ebuf[k];
        ent[nent++] = u;
        atomicAdd(&cnt[u >> 17], 1);
    }
    __syncthreads();

    if (t < 128) sc[t] = cnt[t];
    __syncthreads();
    for (int off = 1; off < 128; off <<= 1) {
        int v = 0;
        if (t < 128 && t >= off) v = sc[t - off];
        __syncthreads();
        if (t < 128) sc[t] += v;
        __syncthreads();
    }
    if (t < 128) {
        int st = s + sc[t] - cnt[t];   // exclusive start
        int node = b * 128 + t;
        if (node < NN) {
            row[node] = st;
            norm_d[node] = rsqrtf((float)(cnt[t] + 1));
        }
        cnt[t] = st;                   // becomes cursor
    }
    if (b == B - 1 && t == 0) row[NN] = NE;
    __syncthreads();

    for (int i = 0; i < nent; ++i) {
        unsigned u = ent[i];
        int pos = atomicAdd(&cnt[u >> 17], 1);
        ebuf[pos] = u & 0x1FFFFu;      // strip bucket bits -> plain src id
    }
}

// ---------------- CSR gather-aggregate over bf16 rows, fp32 accumulate --------
// One wave per dst node; lane owns columns 2*lane, 2*lane+1 (one u32 pair).
// Pure sum: norm_s pre-folded into the bf16 source. Self-loop = init.

__global__ __launch_bounds__(256) void csr_agg(
    const int* __restrict__ row, const int* __restrict__ csr,
    const unsigned* __restrict__ hp, float* __restrict__ agg)
{
    int i = blockIdx.x * 4 + (threadIdx.x >> 6);
    if (i >= NN) return;
    int lane = threadIdx.x & 63;

    float2 acc;
    {
        unsigned u = hp[(size_t)i * 64 + lane];
        acc.x = __uint_as_float(u << 16);
        acc.y = __uint_as_float(u & 0xffff0000u);
    }

    int start = row[i], end = row[i + 1];
    for (int base = start; base < end; base += 64) {
        int n = end - base; if (n > 64) n = 64;
        int sv = csr[base + (lane < n ? lane : n - 1)];
        int j = 0;
        for (; j + 8 <= n; j += 8) {
            int ss[8]; unsigned uu[8];
            #pragma unroll
            for (int t = 0; t < 8; ++t) ss[t] = __shfl(sv, j + t);
            #pragma unroll
            for (int t = 0; t < 8; ++t) uu[t] = hp[(size_t)ss[t] * 64 + lane];
            #pragma unroll
            for (int t = 0; t < 8; ++t) {
                acc.x += __uint_as_float(uu[t] << 16);
                acc.y += __uint_as_float(uu[t] & 0xffff0000u);
            }
        }
        for (; j < n; ++j) {
            int s = __shfl(sv, j);
            unsigned u = hp[(size_t)s * 64 + lane];
            acc.x += __uint_as_float(u << 16);
            acc.y += __uint_as_float(u & 0xffff0000u);
        }
    }
    *(float2*)(agg + (size_t)i * D + 2 * lane) = acc;
}

// ---------------- fused GEMM (+ norm_dst, bias, BN, leaky, norm_src) ----------------
// LAYER0 writes bf16 activations (norm_src folded); LAYER1 writes fp32 output.

template<bool LAYER0>
__global__ __launch_bounds__(256, 2) void gemm_kernel(
    const float* __restrict__ agg, const float* __restrict__ W,
    const float* __restrict__ bias,
    const float* __restrict__ norm_s, const float* __restrict__ norm_d,
    const float* __restrict__ gamma, const float* __restrict__ beta,
    const float* __restrict__ rmean, const float* __restrict__ rvar,
    float* __restrict__ outf, unsigned short* __restrict__ outb)
{
    __shared__ float Wl[D * D];
    for (int idx = threadIdx.x; idx < D * D / 4; idx += 256)
        ((float4*)Wl)[idx] = ((const float4*)W)[idx];
    __syncthreads();

    const int wave = threadIdx.x >> 6;
    const int lane = threadIdx.x & 63;
    const int j0 = lane, j1 = lane + 64;

    const float b0 = bias[j0], b1v = bias[j1];
    float s0 = 0.f, sh0 = 0.f, s1 = 0.f, sh1 = 0.f;
    if (LAYER0) {
        s0  = gamma[j0] * rsqrtf(rvar[j0] + BNEPS);
        sh0 = beta[j0] - rmean[j0] * s0;
        s1  = gamma[j1] * rsqrtf(rvar[j1] + BNEPS);
        sh1 = beta[j1] - rmean[j1] * s1;
    }

    const int ROWS = 4;
    const int wave_id = blockIdx.x * 4 + wave;
    const int nwaves = gridDim.x * 4;
    for (int base = wave_id * ROWS; base < NN; base += nwaves * ROWS) {
        float acc[ROWS][2] = {};
        const float* rp = agg + (size_t)base * D;
        #pragma unroll 4
        for (int k = 0; k < D; k += 4) {
            float vv[ROWS][4];
            *(float4*)&vv[0][0] = *(const float4*)(rp + 0 * D + k);
            *(float4*)&vv[1][0] = *(const float4*)(rp + 1 * D + k);
            *(float4*)&vv[2][0] = *(const float4*)(rp + 2 * D + k);
            *(float4*)&vv[3][0] = *(const float4*)(rp + 3 * D + k);
            #pragma unroll
            for (int kk = 0; kk < 4; ++kk) {
                float w0 = Wl[(k + kk) * D + j0];
                float w1 = Wl[(k + kk) * D + j1];
                #pragma unroll
                for (int r = 0; r < ROWS; ++r) {
                    acc[r][0] = fmaf(vv[r][kk], w0, acc[r][0]);
                    acc[r][1] = fmaf(vv[r][kk], w1, acc[r][1]);
                }
            }
        }
        #pragma unroll
        for (int r = 0; r < ROWS; ++r) {
            int row = base + r;
            float nd = norm_d[row];
            float o0 = acc[r][0] * nd + b0;
            float o1 = acc[r][1] * nd + b1v;
            if (LAYER0) {
                o0 = o0 * s0 + sh0;
                o1 = o1 * s1 + sh1;
                o0 = o0 > 0.f ? o0 : LEAKY * o0;
                o1 = o1 > 0.f ? o1 : LEAKY * o1;
                float ns = norm_s[row];
                o0 *= ns; o1 *= ns;
                outb[(size_t)row * D + j0] = (unsigned short)f2bf(o0);
                outb[(size_t)row * D + j1] = (unsigned short)f2bf(o1);
            } else {
                outf[(size_t)row * D + j0] = o0;
                outf[(size_t)row * D + j1] = o1;
            }
        }
    }
}

// ---------------- launch ----------------

extern "C" void kernel_launch(void* const* d_in, const int* in_sizes, int n_in,
                              void* d_out, int out_size, void* d_ws, size_t ws_size,
                              hipStream_t stream) {
    const float* x     = (const float*)d_in[0];
    const int*   src   = (const int*)d_in[1];
    const int*   dst   = (const int*)d_in[2];
    const float* W1    = (const float*)d_in[3];
    const float* b1    = (const float*)d_in[4];
    const float* W2    = (const float*)d_in[5];
    const float* b2    = (const float*)d_in[6];
    const float* gamma = (const float*)d_in[7];
    const float* beta  = (const float*)d_in[8];
    const float* rmean = (const float*)d_in[9];
    const float* rvar  = (const float*)d_in[10];
    float* out = (float*)d_out;

    // bf16 gather-source scratch lives in d_out's first half (dead until the
    // final GEMM overwrites all of d_out with fp32 results).
    unsigned* hb = (unsigned*)d_out;                    // NN*64 u32 = 25.6 MB

    // ws layout (4B units)
    float*    buf1  = (float*)d_ws;                     // NN*D aggregator
    float*    norm  = buf1 + (size_t)NN * D;            // 2N f32
    int*      hist  = (int*)(norm + 2 * NN);            // B*G int; row[] aliases after scanC
    int*      offs  = hist + B * G;                     // B*G int
    int*      bsum  = offs + B * G;                     // B int
    int*      boffs = bsum + B;                         // B int
    unsigned* ebuf  = (unsigned*)(boffs + B);           // NE u32
    float* norm_s = norm;
    float* norm_d = norm + NN;
    int*   row    = hist;                // aliases hist (dead after scanC)
    int*   deg_s  = (int*)ebuf;          // aliases ebuf head (dead before sort_kernel)

    // out-degree (src) -> norm_s -> bf16 pre-scaled x
    hipMemsetAsync(deg_s, 0, NN * sizeof(int), stream);
    deg_src_kernel<<<(NE + 255) / 256, 256, 0, stream>>>(src, deg_s);
    norm_s_kernel<<<(NN + 255) / 256, 256, 0, stream>>>(deg_s, norm_s);
    conv_kernel<<<(NN * 64 + 255) / 256, 256, 0, stream>>>(x, norm_s, hb);

    // counting sort by dst bucket, then per-bucket local sort -> per-node CSR
    hist_kernel<<<G, 256, 0, stream>>>(dst, hist);
    scanA<<<B * G / 256, 256, 0, stream>>>(hist, bsum);
    scanB<<<1, 64, 0, stream>>>(bsum, boffs);
    scanC<<<B * G / 256, 256, 0, stream>>>(hist, boffs, offs);
    sort_kernel<<<G, 256, 0, stream>>>(src, dst, offs, ebuf);
    local_sort<<<B, 256, 0, stream>>>(offs, ebuf, row, norm_d);

    const int AGG_BLOCKS = (NN + 3) / 4;
    // layer 0: agg = selfloop + sum_e xs[src]   (xs = x*ns in bf16)
    csr_agg<<<AGG_BLOCKS, 256, 0, stream>>>(row, (const int*)ebuf, hb, buf1);
    gemm_kernel<true><<<512, 256, 0, stream>>>(buf1, W1, b1, norm_s, norm_d,
                                               gamma, beta, rmean, rvar,
                                               nullptr, (unsigned short*)hb);
    // layer 1: gather source = bf16 hs (norm_src folded)
    csr_agg<<<AGG_BLOCKS, 256, 0, stream>>>(row, (const int*)ebuf, hb, buf1);
    gemm_kernel<false><<<512, 256, 0, stream>>>(buf1, W2, b2, norm_s, norm_d,
                                                nullptr, nullptr, nullptr, nullptr,
                                                out, nullptr);
}

// Round 6
// 466.469 us; speedup vs baseline: 6.7781x; 1.2454x over previous
//
#include <hip/hip_runtime.h>

#define NN 100000
#define NE 1600000
#define D 128
#define LEAKY 0.01f
#define BNEPS 1e-5f

#define G 256        // sort groups (workgroups)
#define CHUNK 6250   // NE / G exactly
#define B 782        // ceil(NN/128) dst-buckets
#define BSHIFT 7
#define BMASK 127

typedef short v8s __attribute__((ext_vector_type(8)));
typedef float v4f __attribute__((ext_vector_type(4)));

// round-to-nearest-even f32 -> bf16 (returns low 16 bits)
__device__ __forceinline__ unsigned f2bf(float f) {
    unsigned u = __float_as_uint(f);
    return (u + 0x7fffu + ((u >> 16) & 1u)) >> 16;
}
__device__ __forceinline__ float bf2f(unsigned h) {
    return __uint_as_float(h << 16);
}

// ---------------- out-degree + norm_s (in-degree comes from local_sort) ----------

__global__ void deg_src_kernel(const int* __restrict__ src, int* __restrict__ deg) {
    int e = blockIdx.x * blockDim.x + threadIdx.x;
    if (e < NE) atomicAdd(&deg[src[e]], 1);
}

__global__ void norm_s_kernel(const int* __restrict__ deg, float* __restrict__ norm_s) {
    int i = blockIdx.x * blockDim.x + threadIdx.x;
    if (i < NN) norm_s[i] = rsqrtf((float)(deg[i] + 1));   // +1 = self-loop
}

// ---------------- x * norm_s -> bf16 gather source ----------------

__global__ __launch_bounds__(256) void conv_kernel(const float* __restrict__ x,
                                                   const float* __restrict__ norm_s,
                                                   unsigned* __restrict__ hb) {
    int t = blockIdx.x * 256 + threadIdx.x;     // one u32 pair per thread
    if (t >= NN * 64) return;
    float ns = norm_s[t >> 6];
    float2 v = ((const float2*)x)[t];
    hb[t] = f2bf(v.x * ns) | (f2bf(v.y * ns) << 16);
}

// ---------------- counting sort by dst bucket ----------------

__global__ __launch_bounds__(256) void hist_kernel(const int* __restrict__ dst,
                                                   int* __restrict__ hist) {
    __shared__ int h[B];
    for (int i = threadIdx.x; i < B; i += 256) h[i] = 0;
    __syncthreads();
    int g = blockIdx.x;
    const int* dp = dst + g * CHUNK;
    for (int k = threadIdx.x; k < CHUNK; k += 256)
        atomicAdd(&h[dp[k] >> BSHIFT], 1);
    __syncthreads();
    for (int i = threadIdx.x; i < B; i += 256) hist[i * G + g] = h[i];
}

__global__ void scanA(const int* __restrict__ a, int* __restrict__ bsum) {
    __shared__ int sm[256];
    int t = threadIdx.x;
    sm[t] = a[blockIdx.x * 256 + t];
    __syncthreads();
    for (int s = 128; s > 0; s >>= 1) {
        if (t < s) sm[t] += sm[t + s];
        __syncthreads();
    }
    if (t == 0) bsum[blockIdx.x] = sm[0];
}

__global__ void scanB(const int* __restrict__ bsum, int* __restrict__ boffs) {
    int lane = threadIdx.x;
    int run = 0;
    for (int base = 0; base < B; base += 64) {
        int i = base + lane;
        int v = (i < B) ? bsum[i] : 0;
        int orig = v;
        for (int off = 1; off < 64; off <<= 1) {
            int t = __shfl_up(v, off);
            if (lane >= off) v += t;
        }
        if (i < B) boffs[i] = run + v - orig;   // exclusive
        run += __shfl(v, 63);
    }
}

__global__ void scanC(const int* __restrict__ a, const int* __restrict__ boffs,
                      int* __restrict__ offs) {
    __shared__ int sm[256];
    int t = threadIdx.x;
    int i = blockIdx.x * 256 + t;
    int v = a[i];
    sm[t] = v;
    __syncthreads();
    for (int off = 1; off < 256; off <<= 1) {
        int x = (t >= off) ? sm[t - off] : 0;
        __syncthreads();
        sm[t] += x;
        __syncthreads();
    }
    offs[i] = boffs[blockIdx.x] + sm[t] - v;    // exclusive
}

__global__ __launch_bounds__(256) void sort_kernel(const int* __restrict__ src,
                                                   const int* __restrict__ dst,
                                                   const int* __restrict__ offs,
                                                   unsigned* __restrict__ ebuf) {
    __shared__ int cur[B];
    int g = blockIdx.x;
    for (int i = threadIdx.x; i < B; i += 256) cur[i] = offs[i * G + g];
    __syncthreads();
    const int* sp = src + g * CHUNK;
    const int* dp = dst + g * CHUNK;
    for (int k = threadIdx.x; k < CHUNK; k += 256) {
        int d = dp[k], s = sp[k];
        int pos = atomicAdd(&cur[d >> BSHIFT], 1);
        ebuf[pos] = ((unsigned)(d & BMASK) << 17) | (unsigned)s;   // src < 2^17
    }
}

// ---------------- per-bucket local sort: bucket order -> per-node CSR ----------

__global__ __launch_bounds__(256) void local_sort(
    const int* __restrict__ offs, unsigned* __restrict__ ebuf,
    int* __restrict__ row, float* __restrict__ norm_d)
{
    __shared__ int cnt[128];
    __shared__ int sc[128];
    const int b = blockIdx.x;
    const int t = threadIdx.x;
    const int s = offs[b * G];
    const int e = (b == B - 1) ? NE : offs[(b + 1) * G];
    if (t < 128) cnt[t] = 0;
    __syncthreads();

    unsigned ent[16];   // 16*256 = 4096 capacity; bucket mean 2048, sd ~45
    int nent = 0;
    for (int k = s + t; k < e && nent < 16; k += 256) {
        unsigned u = ebuf[k];
        ent[nent++] = u;
        atomicAdd(&cnt[u >> 17], 1);
    }
    __syncthreads();

    if (t < 128) sc[t] = cnt[t];
    __syncthreads();
    for (int off = 1; off < 128; off <<= 1) {
        int v = 0;
        if (t < 128 && t >= off) v = sc[t - off];
        __syncthreads();
        if (t < 128) sc[t] += v;
        __syncthreads();
    }
    if (t < 128) {
        int st = s + sc[t] - cnt[t];   // exclusive start
        int node = b * 128 + t;
        if (node < NN) {
            row[node] = st;
            norm_d[node] = rsqrtf((float)(cnt[t] + 1));
        }
        cnt[t] = st;                   // becomes cursor
    }
    if (b == B - 1 && t == 0) row[NN] = NE;
    __syncthreads();

    for (int i = 0; i < nent; ++i) {
        unsigned u = ent[i];
        int pos = atomicAdd(&cnt[u >> 17], 1);
        ebuf[pos] = u & 0x1FFFFu;      // strip bucket bits -> plain src id
    }
}

// ---------------- CSR gather-aggregate over bf16 rows, fp32 accumulate --------
// Output: split-precision bf16 hi/lo planes (for the MFMA GEMM).

__global__ __launch_bounds__(256) void csr_agg(
    const int* __restrict__ row, const int* __restrict__ csr,
    const unsigned* __restrict__ hp,
    unsigned* __restrict__ Ahi, unsigned* __restrict__ Alo)
{
    int i = blockIdx.x * 4 + (threadIdx.x >> 6);
    if (i >= NN) return;
    int lane = threadIdx.x & 63;

    float2 acc;
    {
        unsigned u = hp[(size_t)i * 64 + lane];
        acc.x = __uint_as_float(u << 16);
        acc.y = __uint_as_float(u & 0xffff0000u);
    }

    int start = row[i], end = row[i + 1];
    for (int base = start; base < end; base += 64) {
        int n = end - base; if (n > 64) n = 64;
        int sv = csr[base + (lane < n ? lane : n - 1)];
        int j = 0;
        for (; j + 8 <= n; j += 8) {
            int ss[8]; unsigned uu[8];
            #pragma unroll
            for (int t = 0; t < 8; ++t) ss[t] = __shfl(sv, j + t);
            #pragma unroll
            for (int t = 0; t < 8; ++t) uu[t] = hp[(size_t)ss[t] * 64 + lane];
            #pragma unroll
            for (int t = 0; t < 8; ++t) {
                acc.x += __uint_as_float(uu[t] << 16);
                acc.y += __uint_as_float(uu[t] & 0xffff0000u);
            }
        }
        for (; j < n; ++j) {
            int s = __shfl(sv, j);
            unsigned u = hp[(size_t)s * 64 + lane];
            acc.x += __uint_as_float(u << 16);
            acc.y += __uint_as_float(u & 0xffff0000u);
        }
    }
    unsigned hx = f2bf(acc.x), hy = f2bf(acc.y);
    float lx = acc.x - bf2f(hx), ly = acc.y - bf2f(hy);
    Ahi[(size_t)i * 64 + lane] = hx | (hy << 16);
    Alo[(size_t)i * 64 + lane] = f2bf(lx) | (f2bf(ly) << 16);
}

// ---------------- MFMA GEMM, split-precision bf16 (3-mfma ~ fp32 accuracy) -----
// Block = 4 waves; wave w owns cols [32w, 32w+32) with all B-fragments (hi+lo)
// in VGPRs. 64 A-rows staged per iter into padded LDS (row stride 136 bf16 ->
// 2-way bank aliasing only). D = Ahi*Whi + Alo*Whi + Ahi*Wlo.
// Epilogue folds norm_dst, bias, (BN, leaky, norm_src for layer 0).

template<bool LAYER0>
__global__ __launch_bounds__(256) void gemm_kernel(
    const unsigned* __restrict__ Ahi_g, const unsigned* __restrict__ Alo_g,
    const float* __restrict__ W, const float* __restrict__ bias,
    const float* __restrict__ norm_s, const float* __restrict__ norm_d,
    const float* __restrict__ gamma, const float* __restrict__ beta,
    const float* __restrict__ rmean, const float* __restrict__ rvar,
    float* __restrict__ outf, unsigned short* __restrict__ outb)
{
    __shared__ unsigned lhi[64 * 68];   // 64 rows x 136 bf16 (pad 8)
    __shared__ unsigned llo[64 * 68];

    const int w    = threadIdx.x >> 6;
    const int lane = threadIdx.x & 63;
    const int quad = lane >> 4;
    const int l16  = lane & 15;

    // ---- B fragments (hi/lo) for this wave's 2 col-tiles, all K ----
    v8s Bhi[2][4], Blo[2][4];
    int col[2];
    #pragma unroll
    for (int ct = 0; ct < 2; ++ct) {
        col[ct] = 32 * w + 16 * ct + l16;
        #pragma unroll
        for (int q = 0; q < 4; ++q) {
            int kb = 32 * q + quad * 8;
            v8s hi8, lo8;
            #pragma unroll
            for (int kk = 0; kk < 8; ++kk) {
                float wv = W[(kb + kk) * D + col[ct]];
                unsigned h = f2bf(wv);
                hi8[kk] = (short)h;
                lo8[kk] = (short)f2bf(wv - bf2f(h));
            }
            Bhi[ct][q] = hi8;
            Blo[ct][q] = lo8;
        }
    }

    // per-column epilogue constants
    float bcol[2], s[2] = {0.f, 0.f}, sh[2] = {0.f, 0.f};
    #pragma unroll
    for (int ct = 0; ct < 2; ++ct) {
        bcol[ct] = bias[col[ct]];
        if (LAYER0) {
            s[ct]  = gamma[col[ct]] * rsqrtf(rvar[col[ct]] + BNEPS);
            sh[ct] = beta[col[ct]] - rmean[col[ct]] * s[ct];
        }
    }

    for (int row0 = blockIdx.x * 64; row0 < NN; row0 += gridDim.x * 64) {
        __syncthreads();
        // stage 64 rows of Ahi/Alo (u32-pair packed) into padded LDS
        for (int idx = threadIdx.x; idx < 64 * 64; idx += 256) {
            int r = idx >> 6, cp = idx & 63;
            int rw = row0 + r;
            unsigned vh = 0, vl = 0;
            if (rw < NN) {
                vh = Ahi_g[(size_t)rw * 64 + cp];
                vl = Alo_g[(size_t)rw * 64 + cp];
            }
            lhi[r * 68 + cp] = vh;
            llo[r * 68 + cp] = vl;
        }
        __syncthreads();

        #pragma unroll
        for (int rt = 0; rt < 4; ++rt) {
            v4f acc0 = {0.f, 0.f, 0.f, 0.f};
            v4f acc1 = {0.f, 0.f, 0.f, 0.f};
            #pragma unroll
            for (int q = 0; q < 4; ++q) {
                // A fragment: row = rt*16 + l16, k = q*32 + quad*8 .. +7
                const unsigned short* ph = (const unsigned short*)lhi
                    + (rt * 16 + l16) * 136 + q * 32 + quad * 8;
                const unsigned short* pl = (const unsigned short*)llo
                    + (rt * 16 + l16) * 136 + q * 32 + quad * 8;
                v8s ahi = *(const v8s*)ph;
                v8s alo = *(const v8s*)pl;
                acc0 = __builtin_amdgcn_mfma_f32_16x16x32_bf16(ahi, Bhi[0][q], acc0, 0, 0, 0);
                acc0 = __builtin_amdgcn_mfma_f32_16x16x32_bf16(alo, Bhi[0][q], acc0, 0, 0, 0);
                acc0 = __builtin_amdgcn_mfma_f32_16x16x32_bf16(ahi, Blo[0][q], acc0, 0, 0, 0);
                acc1 = __builtin_amdgcn_mfma_f32_16x16x32_bf16(ahi, Bhi[1][q], acc1, 0, 0, 0);
                acc1 = __builtin_amdgcn_mfma_f32_16x16x32_bf16(alo, Bhi[1][q], acc1, 0, 0, 0);
                acc1 = __builtin_amdgcn_mfma_f32_16x16x32_bf16(ahi, Blo[1][q], acc1, 0, 0, 0);
            }
            // epilogue: C/D layout col=lane&15 (within tile), row=quad*4+reg
            #pragma unroll
            for (int r = 0; r < 4; ++r) {
                int rw = row0 + rt * 16 + quad * 4 + r;
                if (rw >= NN) continue;
                float nd = norm_d[rw];
                float o0 = acc0[r] * nd + bcol[0];
                float o1 = acc1[r] * nd + bcol[1];
                if (LAYER0) {
                    o0 = o0 * s[0] + sh[0];
                    o1 = o1 * s[1] + sh[1];
                    o0 = o0 > 0.f ? o0 : LEAKY * o0;
                    o1 = o1 > 0.f ? o1 : LEAKY * o1;
                    float ns = norm_s[rw];
                    o0 *= ns; o1 *= ns;
                    outb[(size_t)rw * D + col[0]] = (unsigned short)f2bf(o0);
                    outb[(size_t)rw * D + col[1]] = (unsigned short)f2bf(o1);
                } else {
                    outf[(size_t)rw * D + col[0]] = o0;
                    outf[(size_t)rw * D + col[1]] = o1;
                }
            }
        }
    }
}

// ---------------- launch ----------------

extern "C" void kernel_launch(void* const* d_in, const int* in_sizes, int n_in,
                              void* d_out, int out_size, void* d_ws, size_t ws_size,
                              hipStream_t stream) {
    const float* x     = (const float*)d_in[0];
    const int*   src   = (const int*)d_in[1];
    const int*   dst   = (const int*)d_in[2];
    const float* W1    = (const float*)d_in[3];
    const float* b1    = (const float*)d_in[4];
    const float* W2    = (const float*)d_in[5];
    const float* b2    = (const float*)d_in[6];
    const float* gamma = (const float*)d_in[7];
    const float* beta  = (const float*)d_in[8];
    const float* rmean = (const float*)d_in[9];
    const float* rvar  = (const float*)d_in[10];
    float* out = (float*)d_out;

    // bf16 gather-source scratch lives in d_out's first half (dead until the
    // final GEMM overwrites all of d_out with fp32 results).
    unsigned* hb = (unsigned*)d_out;                    // NN*64 u32 = 25.6 MB

    // ws layout (4B units)
    unsigned* Ahi   = (unsigned*)d_ws;                  // NN*64 u32 (bf16 hi pairs)
    unsigned* Alo   = Ahi + (size_t)NN * 64;            // NN*64 u32 (bf16 lo pairs)
    float*    norm  = (float*)(Alo + (size_t)NN * 64);  // 2N f32
    int*      hist  = (int*)(norm + 2 * NN);            // B*G int; row[] aliases after scanC
    int*      offs  = hist + B * G;                     // B*G int
    int*      bsum  = offs + B * G;                     // B int
    int*      boffs = bsum + B;                         // B int
    unsigned* ebuf  = (unsigned*)(boffs + B);           // NE u32
    float* norm_s = norm;
    float* norm_d = norm + NN;
    int*   row    = hist;                // aliases hist (dead after scanC)
    int*   deg_s  = (int*)ebuf;          // aliases ebuf head (dead before sort_kernel)

    // out-degree (src) -> norm_s -> bf16 pre-scaled x
    hipMemsetAsync(deg_s, 0, NN * sizeof(int), stream);
    deg_src_kernel<<<(NE + 255) / 256, 256, 0, stream>>>(src, deg_s);
    norm_s_kernel<<<(NN + 255) / 256, 256, 0, stream>>>(deg_s, norm_s);
    conv_kernel<<<(NN * 64 + 255) / 256, 256, 0, stream>>>(x, norm_s, hb);

    // counting sort by dst bucket, then per-bucket local sort -> per-node CSR
    hist_kernel<<<G, 256, 0, stream>>>(dst, hist);
    scanA<<<B * G / 256, 256, 0, stream>>>(hist, bsum);
    scanB<<<1, 64, 0, stream>>>(bsum, boffs);
    scanC<<<B * G / 256, 256, 0, stream>>>(hist, boffs, offs);
    sort_kernel<<<G, 256, 0, stream>>>(src, dst, offs, ebuf);
    local_sort<<<B, 256, 0, stream>>>(offs, ebuf, row, norm_d);

    const int AGG_BLOCKS = (NN + 3) / 4;
    const int GEMM_BLOCKS = 784;   // ~2 row-iters each, ~3 blocks/CU
    // layer 0: agg = selfloop + sum_e xs[src]  -> split bf16 hi/lo
    csr_agg<<<AGG_BLOCKS, 256, 0, stream>>>(row, (const int*)ebuf, hb, Ahi, Alo);
    gemm_kernel<true><<<GEMM_BLOCKS, 256, 0, stream>>>(Ahi, Alo, W1, b1,
                                                       norm_s, norm_d,
                                                       gamma, beta, rmean, rvar,
                                                       nullptr, (unsigned short*)hb);
    // layer 1: gather source = bf16 hs (norm_src folded)
    csr_agg<<<AGG_BLOCKS, 256, 0, stream>>>(row, (const int*)ebuf, hb, Ahi, Alo);
    gemm_kernel<false><<<GEMM_BLOCKS, 256, 0, stream>>>(Ahi, Alo, W2, b2,
                                                        norm_s, norm_d,
                                                        nullptr, nullptr, nullptr, nullptr,
                                                        out, nullptr);
}